// Round 1
// baseline (2483.508 us; speedup 1.0000x reference)
//
#include <hip/hip_runtime.h>
#include <hip/hip_bf16.h>

// Problem constants (from setup_inputs): N=65536 rows, D_LAT=64, K=64, 10 iters
#define NROWS 65536
#define DLAT  64
#define KC    64
#define TILE  128                 // rows per block in kmeans kernel
#define NBLK  (NROWS / TILE)      // 512 blocks
#define NSLICE 8                  // contention-reduction slices for Cnew atomics
#define SLICESZ 4160              // 4096 Cnew + 64 rsum floats per slice
#define SETSZ  (NSLICE * SLICESZ) // floats per iteration accumulator set

// ---------------------------------------------------------------------------
// Decoder loss: sum((X - dec)^2) over 65536*512 f32 elements. HBM-bound.
// ---------------------------------------------------------------------------
__global__ __launch_bounds__(256) void decoder_loss_kernel(
    const float* __restrict__ X, const float* __restrict__ Dec,
    float* __restrict__ out_sum)
{
    const int n4 = NROWS * 512 / 4;  // 8388608 float4s
    int i = blockIdx.x * blockDim.x + threadIdx.x;
    int stride = gridDim.x * blockDim.x;
    float s = 0.f;
    for (int j = i; j < n4; j += stride) {
        float4 a = ((const float4*)X)[j];
        float4 b = ((const float4*)Dec)[j];
        float dx = a.x - b.x, dy = a.y - b.y, dz = a.z - b.z, dw = a.w - b.w;
        s = fmaf(dx, dx, fmaf(dy, dy, fmaf(dz, dz, fmaf(dw, dw, s))));
    }
    #pragma unroll
    for (int off = 32; off; off >>= 1) s += __shfl_down(s, off, 64);
    __shared__ float red[4];
    if ((threadIdx.x & 63) == 0) red[threadIdx.x >> 6] = s;
    __syncthreads();
    if (threadIdx.x == 0) atomicAdd(out_sum, red[0] + red[1] + red[2] + red[3]);
}

// ---------------------------------------------------------------------------
// One soft-kmeans iteration, fused:
//   - stage C into LDS: C = sum_slices(Cnew_prev) / (sum_slices(rsum_prev)+eps)
//     (mode 0: C = enc[:64] directly)
//   - per-thread row: d2 to all 64 centroids, softmax, (mode 2: loss only)
//   - r tile -> LDS (bf16), cooperative r^T@enc rank-1 accumulation,
//     sliced atomics into cur_acc
// ---------------------------------------------------------------------------
__global__ __launch_bounds__(TILE, 1) void kmeans_iter(
    const float* __restrict__ enc,
    const float* __restrict__ prev_acc,   // NSLICE slices of [4096 Cnew | 64 rsum]
    float* __restrict__ cur_acc,
    float* __restrict__ loss_sum,
    int mode)  // 0 = first iter, 1 = middle, 2 = last (loss only, no C update)
{
    __shared__ float Cl[KC * DLAT];       // C[k][d], 16 KB
    __shared__ float c2[KC];
    __shared__ float rsl[KC];
    __shared__ __hip_bfloat16 rl[TILE * 66];  // r tile, pitch 66 avoids conflicts
    __shared__ float lred[2];

    const int t = threadIdx.x;
    const int row = blockIdx.x * TILE + t;

    // ---- stage C ----
    if (mode == 0) {
        for (int j = 0; j < (KC * DLAT) / TILE; ++j) {
            int idx = t + j * TILE;
            Cl[idx] = enc[idx];           // C init = enc[:64] (first 4096 floats)
        }
    } else {
        if (t < KC) {
            float v = 0.f;
            #pragma unroll
            for (int sl = 0; sl < NSLICE; ++sl)
                v += prev_acc[sl * SLICESZ + 4096 + t];
            rsl[t] = v + 1e-8f;
        }
        __syncthreads();
        for (int j = 0; j < (KC * DLAT) / TILE; ++j) {
            int idx = t + j * TILE;       // coalesced over slices
            float cs = 0.f;
            #pragma unroll
            for (int sl = 0; sl < NSLICE; ++sl)
                cs += prev_acc[sl * SLICESZ + idx];
            Cl[idx] = cs / rsl[idx >> 6];
        }
    }
    __syncthreads();
    if (t < KC) {
        float s = 0.f;
        #pragma unroll
        for (int d = 0; d < DLAT; ++d) { float v = Cl[t * DLAT + d]; s = fmaf(v, v, s); }
        c2[t] = s;
    }
    __syncthreads();

    // ---- phase 1: this thread's row -> d2[64] -> softmax ----
    const float4* xr = (const float4*)(enc + (size_t)row * DLAT);
    float4 xs[16];
    #pragma unroll
    for (int j = 0; j < 16; ++j) xs[j] = xr[j];

    float x2 = 0.f;
    #pragma unroll
    for (int j = 0; j < 16; ++j) {
        float4 x = xs[j];
        x2 = fmaf(x.x, x.x, fmaf(x.y, x.y, fmaf(x.z, x.z, fmaf(x.w, x.w, x2))));
    }

    float acc[KC];
    #pragma unroll
    for (int k = 0; k < KC; ++k) acc[k] = 0.f;
    for (int d4 = 0; d4 < 16; ++d4) {       // outer rolled, inner unrolled
        float4 x = xs[d4];
        #pragma unroll
        for (int k = 0; k < KC; ++k) {
            float4 c = *(const float4*)(&Cl[k * DLAT + d4 * 4]);  // LDS broadcast
            acc[k] = fmaf(x.x, c.x, fmaf(x.y, c.y, fmaf(x.z, c.z, fmaf(x.w, c.w, acc[k]))));
        }
    }

    float dmin = 3.4e38f;
    #pragma unroll
    for (int k = 0; k < KC; ++k) {
        float d2 = fmaxf(x2 + c2[k] - 2.f * acc[k], 0.f);
        acc[k] = d2;
        dmin = fminf(dmin, d2);
    }
    float l = 0.f, swd = 0.f;
    #pragma unroll
    for (int k = 0; k < KC; ++k) {
        float e = __expf(dmin - acc[k]);    // softmax(-d2) with max-trick
        l += e;
        swd = fmaf(e, acc[k], swd);
        acc[k] = e;
    }
    float inv_l = 1.f / l;                   // l >= 1 always

    if (mode == 2) {
        // loss of the final iteration only
        float li = swd * inv_l;
        #pragma unroll
        for (int off = 32; off; off >>= 1) li += __shfl_down(li, off, 64);
        if ((t & 63) == 0) lred[t >> 6] = li;
        __syncthreads();
        if (t == 0) atomicAdd(loss_sum, lred[0] + lred[1]);
        return;
    }

    // store normalized r into LDS (bf16; tolerance is very loose on cluster term)
    #pragma unroll
    for (int k = 0; k < KC; ++k)
        rl[t * 66 + k] = __float2bfloat16(acc[k] * inv_l);
    __syncthreads();

    // ---- phase 2: Cnew += r^T @ enc over this block's tile ----
    const int k  = t >> 1;           // 0..63
    const int d0 = (t & 1) * 32;     // 0 or 32
    float cacc[32];
    #pragma unroll
    for (int j = 0; j < 32; ++j) cacc[j] = 0.f;
    float rs = 0.f;
    const float* encb = enc + (size_t)blockIdx.x * TILE * DLAT;
    for (int i = 0; i < TILE; ++i) {
        float r = __bfloat162float(rl[i * 66 + k]);
        rs += r;
        const float4* er = (const float4*)(encb + i * DLAT + d0);
        #pragma unroll
        for (int j4 = 0; j4 < 8; ++j4) {
            float4 e = er[j4];      // L1-hot (loaded by phase 1 on same CU)
            cacc[j4 * 4 + 0] = fmaf(r, e.x, cacc[j4 * 4 + 0]);
            cacc[j4 * 4 + 1] = fmaf(r, e.y, cacc[j4 * 4 + 1]);
            cacc[j4 * 4 + 2] = fmaf(r, e.z, cacc[j4 * 4 + 2]);
            cacc[j4 * 4 + 3] = fmaf(r, e.w, cacc[j4 * 4 + 3]);
        }
    }
    float* slice = cur_acc + (size_t)(blockIdx.x & (NSLICE - 1)) * SLICESZ;
    #pragma unroll
    for (int j = 0; j < 32; ++j)
        atomicAdd(&slice[k * DLAT + d0 + j], cacc[j]);
    if ((t & 1) == 0) atomicAdd(&slice[4096 + k], rs);
}

// ---------------------------------------------------------------------------
__global__ void finalize_kernel(const float* __restrict__ dec_sum,
                                const float* __restrict__ loss_sum,
                                float* __restrict__ out)
{
    out[0] = dec_sum[0] * (1.f / (65536.f * 512.f))
           + 0.001f * (loss_sum[0] * (1.f / 65536.f));
}

// ---------------------------------------------------------------------------
extern "C" void kernel_launch(void* const* d_in, const int* in_sizes, int n_in,
                              void* d_out, int out_size, void* d_ws, size_t ws_size,
                              hipStream_t stream)
{
    const float* X   = (const float*)d_in[0];
    const float* enc = (const float*)d_in[1];
    const float* dec = (const float*)d_in[2];
    // d_in[3] = K (scalar, always 64 here) — compile-time constant

    float* out = (float*)d_out;
    float* ws  = (float*)d_ws;

    float* dec_sum  = ws + 0;
    float* loss_sum = ws + 1;
    float* sets     = ws + 16;   // 9 iteration sets of SETSZ floats each

    // zero accumulators (ws is poisoned 0xAA before every launch)
    size_t zero_bytes = (size_t)(16 + 9 * SETSZ) * sizeof(float);  // ~1.2 MB
    hipMemsetAsync(d_ws, 0, zero_bytes, stream);

    decoder_loss_kernel<<<dim3(2048), dim3(256), 0, stream>>>(X, dec, dec_sum);

    for (int it = 0; it < 10; ++it) {
        int mode = (it == 0) ? 0 : ((it == 9) ? 2 : 1);
        const float* prev = (it == 0) ? sets : sets + (size_t)(it - 1) * SETSZ;
        float* cur = (it < 9) ? sets + (size_t)it * SETSZ : sets; // unused when mode==2
        kmeans_iter<<<dim3(NBLK), dim3(TILE), 0, stream>>>(enc, prev, cur, loss_sum, mode);
    }

    finalize_kernel<<<1, 1, 0, stream>>>(dec_sum, loss_sum, out);
}

// Round 2
// 840.399 us; speedup vs baseline: 2.9552x; 2.9552x over previous
//
#include <hip/hip_runtime.h>

typedef __attribute__((ext_vector_type(8))) short bf16x8;
typedef __attribute__((ext_vector_type(4))) float f32x4;

#define NROWS   65536
#define NSLICE  8
#define SLICESZ 4160
#define SETSZ   (NSLICE*SLICESZ)   // 33280 floats
#define EPSV    1e-8f

// ---- ws layout (float offsets) ----
#define WS_DEC   0
#define WS_LOSS  1
#define WS_SETA  16
#define WS_SETB  (WS_SETA + SETSZ)          // 33296
#define WS_X2    (WS_SETB + SETSZ)          // 66576
#define WS_C2    (WS_X2 + NROWS)            // 132112
#define WS_CBF   132176                      // CBfrag: 4096 bf16 (2048 floats), 16B aligned
#define WS_ENCB  134224                      // encB: 4194304 bf16 (2097152 floats)
#define WS_EBF   (WS_ENCB + 2097152)         // encBfrag: 4194304 bf16
#define WS_END   (WS_EBF + 2097152)          // ~17.3 MB total

static __device__ __forceinline__ unsigned short f2bf(float f) {
    union { float f; unsigned u; } v; v.f = f;
    unsigned u = v.u + 0x7fffu + ((v.u >> 16) & 1u);
    return (unsigned short)(u >> 16);
}
static __device__ __forceinline__ float bf2f(unsigned short h) {
    union { unsigned u; float f; } v; v.u = ((unsigned)h) << 16; return v.f;
}
static __device__ __forceinline__ uint4 pack8(const unsigned short* h) {
    uint4 o;
    o.x = h[0] | ((unsigned)h[1] << 16);
    o.y = h[2] | ((unsigned)h[3] << 16);
    o.z = h[4] | ((unsigned)h[5] << 16);
    o.w = h[6] | ((unsigned)h[7] << 16);
    return o;
}

// ---------------------------------------------------------------------------
// Decoder loss: sum((X - dec)^2), HBM-bound (proven in round 1).
// ---------------------------------------------------------------------------
__global__ __launch_bounds__(256) void decoder_loss_kernel(
    const float* __restrict__ X, const float* __restrict__ Dec,
    float* __restrict__ out_sum)
{
    const int n4 = NROWS * 512 / 4;
    int i = blockIdx.x * blockDim.x + threadIdx.x;
    int stride = gridDim.x * blockDim.x;
    float s = 0.f;
    for (int j = i; j < n4; j += stride) {
        float4 a = ((const float4*)X)[j];
        float4 b = ((const float4*)Dec)[j];
        float dx = a.x - b.x, dy = a.y - b.y, dz = a.z - b.z, dw = a.w - b.w;
        s = fmaf(dx, dx, fmaf(dy, dy, fmaf(dz, dz, fmaf(dw, dw, s))));
    }
    #pragma unroll
    for (int off = 32; off; off >>= 1) s += __shfl_down(s, off, 64);
    __shared__ float red[4];
    if ((threadIdx.x & 63) == 0) red[threadIdx.x >> 6] = s;
    __syncthreads();
    if (threadIdx.x == 0) atomicAdd(out_sum, red[0] + red[1] + red[2] + red[3]);
}

// ---------------------------------------------------------------------------
// prep0: enc f32 -> encB (bf16, row-major), encBfrag (phase-2 B fragment order),
//        x2[row] = |bf16(enc_row)|^2.  Grid 1024 x 256, 64 rows/block.
// encBfrag flat entry f = rb*256 + dt*64 + lane (8 bf16 each):
//   value j = encB[rb*32 + (lane>>4)*8 + j][dt*16 + (lane&15)]
// ---------------------------------------------------------------------------
__global__ __launch_bounds__(256) void prep0(
    const float* __restrict__ enc, unsigned* __restrict__ encB,
    uint4* __restrict__ encBfrag, float* __restrict__ x2)
{
    __shared__ unsigned short L[64 * 64];
    int t = threadIdx.x;
    int rl = t >> 2, part = t & 3;
    int row = blockIdx.x * 64 + rl;
    const float4* src = (const float4*)(enc + (size_t)row * 64 + part * 16);
    unsigned short hv[16];
    float ss = 0.f;
    #pragma unroll
    for (int i = 0; i < 4; ++i) {
        float4 v = src[i];
        unsigned short a = f2bf(v.x), b = f2bf(v.y), c = f2bf(v.z), d = f2bf(v.w);
        hv[i*4+0] = a; hv[i*4+1] = b; hv[i*4+2] = c; hv[i*4+3] = d;
        float fa = bf2f(a), fb = bf2f(b), fc = bf2f(c), fd = bf2f(d);
        ss = fmaf(fa, fa, fmaf(fb, fb, fmaf(fc, fc, fmaf(fd, fd, ss))));
    }
    unsigned* dst = encB + ((size_t)row * 64 + part * 16) / 2;
    #pragma unroll
    for (int i = 0; i < 8; ++i) dst[i] = (unsigned)hv[2*i] | ((unsigned)hv[2*i+1] << 16);
    #pragma unroll
    for (int i = 0; i < 16; ++i) L[rl * 64 + part * 16 + i] = hv[i];
    ss += __shfl_xor(ss, 1, 64);
    ss += __shfl_xor(ss, 2, 64);
    if (part == 0) x2[row] = ss;
    __syncthreads();
    for (int e = t; e < 512; e += 256) {
        int rbl = e >> 8, dt = (e >> 6) & 3, lane = e & 63;
        int q = lane >> 4, c = lane & 15;
        unsigned short hw[8];
        #pragma unroll
        for (int j = 0; j < 8; ++j)
            hw[j] = L[(rbl * 32 + q * 8 + j) * 64 + dt * 16 + c];
        encBfrag[(size_t)blockIdx.x * 512 + e] = pack8(hw);
    }
}

// ---------------------------------------------------------------------------
// prepC: build C from accumulator slices (or enc rows if init), emit
//   CBfrag (phase-1 B fragment order) + c2 (from bf16-rounded C).
//   Also zeros `zero_set` for the next main iteration.  Grid 8 x 256.
// CBfrag entry (kk,nt,lane): 8 bf16, value j = C[nt*16+(lane&15)][(lane>>4)*8+j+kk*32]
// ---------------------------------------------------------------------------
__global__ __launch_bounds__(256) void prepC(
    const float* __restrict__ src_set, float* __restrict__ zero_set,
    const float* __restrict__ enc, uint4* __restrict__ CBfrag,
    float* __restrict__ c2, int init)
{
    __shared__ float Cs[8 * 64];
    __shared__ float rs8[8];
    int b = blockIdx.x, t = threadIdx.x;
    if (t < 8) {
        float v = 0.f;
        if (!init) {
            #pragma unroll
            for (int sl = 0; sl < NSLICE; ++sl)
                v += src_set[sl * SLICESZ + 4096 + b * 8 + t];
        }
        rs8[t] = v + EPSV;
    }
    __syncthreads();
    int r = t >> 5, col0 = t & 31;
    #pragma unroll
    for (int h = 0; h < 2; ++h) {
        int col = col0 + h * 32;
        int gi = (b * 8 + r) * 64 + col;
        float v;
        if (init) v = enc[gi];
        else {
            float s = 0.f;
            #pragma unroll
            for (int sl = 0; sl < NSLICE; ++sl) s += src_set[sl * SLICESZ + gi];
            v = s / rs8[r];
        }
        Cs[r * 64 + col] = bf2f(f2bf(v));  // bf16-rounded for d2 consistency
    }
    __syncthreads();
    if (t < 8) {
        float s = 0.f;
        for (int d = 0; d < 64; ++d) { float v = Cs[t * 64 + d]; s = fmaf(v, v, s); }
        c2[b * 8 + t] = s;
    }
    if (t < 64) {
        int kk = t >> 5, rem = t & 31, q = rem >> 3, j8 = rem & 7;
        int c = (b & 1) * 8 + j8;
        int lane = q * 16 + c;
        int nt = b >> 1;
        unsigned short hw[8];
        #pragma unroll
        for (int j = 0; j < 8; ++j)
            hw[j] = f2bf(Cs[j8 * 64 + q * 8 + j + kk * 32]);
        CBfrag[(kk * 4 + nt) * 64 + lane] = pack8(hw);
    }
    int gt = b * 256 + t;
    for (int i = gt; i < SETSZ; i += 2048) zero_set[i] = 0.f;
}

// ---------------------------------------------------------------------------
// Main fused iteration. Grid 512 x 256 (4 waves), 128 rows/block, 32/wave.
// Phase 1: S = enc@C^T via 2x(4 nt x 2 kk) mfma 16x16x32 on interleaved
//   16-row subsets (rows R0 + 8q + sub*4 + reg), softmax in C-layout regs.
// Phase 2: the C-layout r fragments ARE the A-operand of r^T@enc for the
//   interleaved row order (k = q*8 + sub*4 + reg). 16 mfma -> Cnew partials.
// Flush: LDS reduce across waves, sliced global atomics.
// ---------------------------------------------------------------------------
__global__ __launch_bounds__(256, 2) void kmeans_main(
    const bf16x8* __restrict__ encB8, const bf16x8* __restrict__ encBfrag8,
    const bf16x8* __restrict__ CBfrag8, const float* __restrict__ c2,
    const float* __restrict__ x2, float* __restrict__ cur_set,
    float* __restrict__ loss_sum, int last)
{
    __shared__ float CnewL[4096];
    __shared__ float rsumL[64];
    int t = threadIdx.x;
    int wave = t >> 6, lane = t & 63, q = lane >> 4, c = lane & 15;

    bf16x8 bfr[2][4];
    #pragma unroll
    for (int kk = 0; kk < 2; ++kk)
        #pragma unroll
        for (int nt = 0; nt < 4; ++nt)
            bfr[kk][nt] = CBfrag8[(kk * 4 + nt) * 64 + lane];
    float c2f[4];
    #pragma unroll
    for (int nt = 0; nt < 4; ++nt) c2f[nt] = c2[nt * 16 + c];

    int R0 = blockIdx.x * 128 + wave * 32;
    const f32x4 z4 = {0.f, 0.f, 0.f, 0.f};
    f32x4 cacc[16];
    #pragma unroll
    for (int i = 0; i < 16; ++i) cacc[i] = z4;
    float rs[4] = {0.f, 0.f, 0.f, 0.f};
    float lossacc = 0.f;
    bf16x8 a2f[4];

    #pragma unroll
    for (int sub = 0; sub < 2; ++sub) {
        int arow = R0 + 8 * (c >> 2) + sub * 4 + (c & 3);
        const bf16x8* ap = encB8 + (size_t)arow * 8 + q;
        bf16x8 a0 = ap[0], a1 = ap[4];
        f32x4 accf[4];
        #pragma unroll
        for (int nt = 0; nt < 4; ++nt) {
            f32x4 s = __builtin_amdgcn_mfma_f32_16x16x32_bf16(a0, bfr[0][nt], z4, 0, 0, 0);
            accf[nt]  = __builtin_amdgcn_mfma_f32_16x16x32_bf16(a1, bfr[1][nt], s,  0, 0, 0);
        }
        #pragma unroll
        for (int reg = 0; reg < 4; ++reg) {
            int row = R0 + 8 * q + sub * 4 + reg;
            float x2r = x2[row];
            float d2[4], mn = 3.4e38f;
            #pragma unroll
            for (int nt = 0; nt < 4; ++nt) {
                float v = fmaxf(x2r + c2f[nt] - 2.f * accf[nt][reg], 0.f);
                d2[nt] = v; mn = fminf(mn, v);
            }
            mn = fminf(mn, __shfl_xor(mn, 1, 64));
            mn = fminf(mn, __shfl_xor(mn, 2, 64));
            mn = fminf(mn, __shfl_xor(mn, 4, 64));
            mn = fminf(mn, __shfl_xor(mn, 8, 64));
            float e[4], s = 0.f, swd = 0.f;
            #pragma unroll
            for (int nt = 0; nt < 4; ++nt) {
                float ev = __expf(mn - d2[nt]);
                e[nt] = ev; s += ev; swd = fmaf(ev, d2[nt], swd);
            }
            s   += __shfl_xor(s, 1, 64);   swd += __shfl_xor(swd, 1, 64);
            s   += __shfl_xor(s, 2, 64);   swd += __shfl_xor(swd, 2, 64);
            s   += __shfl_xor(s, 4, 64);   swd += __shfl_xor(swd, 4, 64);
            s   += __shfl_xor(s, 8, 64);   swd += __shfl_xor(swd, 8, 64);
            float inv = 1.f / s;
            if (last && c == 0) lossacc += swd * inv;
            #pragma unroll
            for (int nt = 0; nt < 4; ++nt) {
                float rv = e[nt] * inv;
                rs[nt] += rv;
                a2f[nt][sub * 4 + reg] = (short)f2bf(rv);
            }
        }
    }

    if (!last) {
        int rb = blockIdx.x * 4 + wave;
        #pragma unroll
        for (int dt = 0; dt < 4; ++dt) {
            bf16x8 b2 = encBfrag8[(size_t)(rb * 4 + dt) * 64 + lane];
            #pragma unroll
            for (int mt = 0; mt < 4; ++mt)
                cacc[mt * 4 + dt] = __builtin_amdgcn_mfma_f32_16x16x32_bf16(
                    a2f[mt], b2, cacc[mt * 4 + dt], 0, 0, 0);
        }
        for (int i = t; i < 4096; i += 256) CnewL[i] = 0.f;
        if (t < 64) rsumL[t] = 0.f;
        __syncthreads();
        #pragma unroll
        for (int mt = 0; mt < 4; ++mt)
            #pragma unroll
            for (int dt = 0; dt < 4; ++dt)
                #pragma unroll
                for (int reg = 0; reg < 4; ++reg)
                    atomicAdd(&CnewL[(mt * 16 + q * 4 + reg) * 64 + dt * 16 + c],
                              cacc[mt * 4 + dt][reg]);
        #pragma unroll
        for (int nt = 0; nt < 4; ++nt) {
            float v = rs[nt];
            v += __shfl_xor(v, 16, 64);
            v += __shfl_xor(v, 32, 64);
            if (q == 0) atomicAdd(&rsumL[nt * 16 + c], v);
        }
        __syncthreads();
        float* slice = cur_set + (size_t)(blockIdx.x & (NSLICE - 1)) * SLICESZ;
        for (int i = t; i < 4096; i += 256) atomicAdd(&slice[i], CnewL[i]);
        if (t < 64) atomicAdd(&slice[4096 + t], rsumL[t]);
    } else {
        #pragma unroll
        for (int off = 32; off; off >>= 1) lossacc += __shfl_down(lossacc, off, 64);
        if (lane == 0) atomicAdd(loss_sum, lossacc);
    }
}

// ---------------------------------------------------------------------------
__global__ void finalize_kernel(const float* __restrict__ dec_sum,
                                const float* __restrict__ loss_sum,
                                float* __restrict__ out)
{
    out[0] = dec_sum[0] * (1.f / (65536.f * 512.f))
           + 0.001f * (loss_sum[0] * (1.f / 65536.f));
}

// ---------------------------------------------------------------------------
extern "C" void kernel_launch(void* const* d_in, const int* in_sizes, int n_in,
                              void* d_out, int out_size, void* d_ws, size_t ws_size,
                              hipStream_t stream)
{
    const float* X   = (const float*)d_in[0];
    const float* enc = (const float*)d_in[1];
    const float* dec = (const float*)d_in[2];

    float* ws = (float*)d_ws;
    float* dec_sum  = ws + WS_DEC;
    float* loss_sum = ws + WS_LOSS;
    float* setA = ws + WS_SETA;
    float* setB = ws + WS_SETB;
    float* x2   = ws + WS_X2;
    float* c2   = ws + WS_C2;
    uint4* CBfrag   = (uint4*)(ws + WS_CBF);
    unsigned* encB  = (unsigned*)(ws + WS_ENCB);
    uint4* encBfrag = (uint4*)(ws + WS_EBF);

    // zero sums + both accumulator sets (~266 KB)
    hipMemsetAsync(d_ws, 0, (size_t)WS_X2 * sizeof(float), stream);

    decoder_loss_kernel<<<dim3(2048), dim3(256), 0, stream>>>(X, dec, dec_sum);
    prep0<<<dim3(1024), dim3(256), 0, stream>>>(enc, encB, encBfrag, x2);
    prepC<<<dim3(8), dim3(256), 0, stream>>>(setA, setA, enc, CBfrag, c2, 1);

    const bf16x8* encB8  = (const bf16x8*)encB;
    const bf16x8* eBf8   = (const bf16x8*)encBfrag;
    const bf16x8* CBf8   = (const bf16x8*)CBfrag;

    for (int it = 0; it < 10; ++it) {
        float* cur = (it & 1) ? setB : setA;
        kmeans_main<<<dim3(512), dim3(256), 0, stream>>>(
            encB8, eBf8, CBf8, c2, x2, cur, loss_sum, it == 9 ? 1 : 0);
        if (it < 9) {
            float* nxt = (it & 1) ? setA : setB;  // set main(it+1) will write
            prepC<<<dim3(8), dim3(256), 0, stream>>>(cur, nxt, enc, CBfrag, c2, 0);
        }
    }
    finalize_kernel<<<1, 1, 0, stream>>>(dec_sum, loss_sum, (float*)d_out);
}